// Round 5
// baseline (29.598 us; speedup 1.0000x reference)
//
#include <hip/hip_runtime.h>

#define GRIDN 256
#define SX (GRIDN * GRIDN)   // x-stride in elements (65536)
#define SY (GRIDN)           // y-stride (256)

// Native vector type for nontemporal builtins (HIP_vector_type<float,4> is
// rejected by __builtin_nontemporal_store on hipcc; ext_vector_type works).
typedef float floatx4 __attribute__((ext_vector_type(4)));

// ---------------------------------------------------------------------------
// 2 particles per thread (stride-split by half so pos loads stay coalesced).
// Probe: if per-CU miss-concurrency (MSHR) bound, this is neutral; if
// per-wave MLP bound, this is -20%+. NT stores free L2/L3 for gather lines.
// out row (12 f32): [drift.x,y,z, L00, 0, 0, L10, L11, 0, L20, L21, L22]
// ---------------------------------------------------------------------------

struct Ainv {
    float M00, M01, M02, T0;
    float M10, M11, M12, T1;
    float M20, M21, M22, T2;
};

__device__ __forceinline__ void process_particle(
    const float* __restrict__ pot, const float* __restrict__ vec,
    const Ainv& A, float px, float py, float pz,
    float* __restrict__ out, int p)
{
    float vxp = A.M00 * px + A.M01 * py + A.M02 * pz + A.T0;
    float vyp = A.M10 * px + A.M11 * py + A.M12 * pz + A.T1;
    float vzp = A.M20 * px + A.M21 * py + A.M22 * pz + A.T2;

    int ix = min(max((int)floorf(vxp), 0), GRIDN - 2);
    int iy = min(max((int)floorf(vyp), 0), GRIDN - 2);
    int iz = min(max((int)floorf(vzp), 0), GRIDN - 2);
    float fx = vxp - (float)ix;
    float fy = vyp - (float)iy;
    float fz = vzp - (float)iz;
    float gx = 1.0f - fx, gy = 1.0f - fy, gz = 1.0f - fz;

    int base = ix * SX + iy * SY + iz;

    // ---- potential gather: 4 z-pairs as float2 ----
    const float* P0 = pot + base;
    float2 zA = *reinterpret_cast<const float2*>(P0);            // c000,c001
    float2 zB = *reinterpret_cast<const float2*>(P0 + SY);       // c010,c011
    float2 zC = *reinterpret_cast<const float2*>(P0 + SX);       // c100,c101
    float2 zD = *reinterpret_cast<const float2*>(P0 + SX + SY);  // c110,c111

    // ---- vector field gather: 4 segments of 24B as float4+float2 ----
    const float* V = vec + (size_t)base * 3;
    const int VY = SY * 3;       // 768
    const int VX = SX * 3;       // 196608

    float4 qa = *reinterpret_cast<const float4*>(V);
    float2 ra = *reinterpret_cast<const float2*>(V + 4);
    float4 qb = *reinterpret_cast<const float4*>(V + VY);
    float2 rb = *reinterpret_cast<const float2*>(V + VY + 4);
    float4 qc = *reinterpret_cast<const float4*>(V + VX);
    float2 rc = *reinterpret_cast<const float2*>(V + VX + 4);
    float4 qd = *reinterpret_cast<const float4*>(V + VX + VY);
    float2 rd = *reinterpret_cast<const float2*>(V + VX + VY + 4);

    float c000 = zA.x, c001 = zA.y;
    float c010 = zB.x, c011 = zB.y;
    float c100 = zC.x, c101 = zC.y;
    float c110 = zD.x, c111 = zD.y;

    // analytic trilinear gradient wrt (fx,fy,fz)
    float wyz00 = gy * gz, wyz01 = gy * fz, wyz10 = fy * gz, wyz11 = fy * fz;
    float dUdfx = (c100 - c000) * wyz00 + (c110 - c010) * wyz10
                + (c101 - c001) * wyz01 + (c111 - c011) * wyz11;
    float dUdfy = ((c010 - c000) * gz + (c011 - c001) * fz) * gx
                + ((c110 - c100) * gz + (c111 - c101) * fz) * fx;
    float dUdfz = ((c001 - c000) * gy + (c011 - c010) * fy) * gx
                + ((c101 - c100) * gy + (c111 - c110) * fy) * fx;

    // chain rule through vox = p @ M^T + t
    float gpx = dUdfx * A.M00 + dUdfy * A.M10 + dUdfz * A.M20;
    float gpy = dUdfx * A.M01 + dUdfy * A.M11 + dUdfz * A.M21;
    float gpz = dUdfx * A.M02 + dUdfy * A.M12 + dUdfz * A.M22;

    const float K_CONF = 10.0f;
    float dr0 = -K_CONF * gpx;
    float dr1 = -K_CONF * gpy;
    float dr2 = -K_CONF * gpz;

    // ---- trilinear blend of vector field ----
    float w000 = gx * wyz00, w001 = gx * wyz01, w010 = gx * wyz10, w011 = gx * wyz11;
    float w100 = fx * wyz00, w101 = fx * wyz01, w110 = fx * wyz10, w111 = fx * wyz11;

    float v0 = w000 * qa.x + w001 * qa.w + w010 * qb.x + w011 * qb.w
             + w100 * qc.x + w101 * qc.w + w110 * qd.x + w111 * qd.w;
    float v1 = w000 * qa.y + w001 * ra.x + w010 * qb.y + w011 * rb.x
             + w100 * qc.y + w101 * rc.x + w110 * qd.y + w111 * rd.x;
    float v2 = w000 * qa.z + w001 * ra.y + w010 * qb.z + w011 * rb.y
             + w100 * qc.z + w101 * rc.y + w110 * qd.z + w111 * rd.y;

    // ---- normalize + diffusion tensor + 3x3 Cholesky ----
    const float EPS_NORM = 1e-9f;
    const float EPS_CHOL = 1e-6f;
    const float D_LONG = 0.0017f, D_TRANS = 0.0002f;

    float nv = sqrtf(v0 * v0 + v1 * v1 + v2 * v2) + EPS_NORM;
    float ux = v0 / nv, uy = v1 / nv, uz = v2 / nv;

    float d00 = D_LONG * ux * ux + D_TRANS * (1.0f - ux * ux) + EPS_CHOL;
    float d11 = D_LONG * uy * uy + D_TRANS * (1.0f - uy * uy) + EPS_CHOL;
    float d22 = D_LONG * uz * uz + D_TRANS * (1.0f - uz * uz) + EPS_CHOL;
    float d10 = (D_LONG - D_TRANS) * uy * ux;
    float d20 = (D_LONG - D_TRANS) * uz * ux;
    float d21 = (D_LONG - D_TRANS) * uz * uy;

    float L00 = sqrtf(d00);
    float L10 = d10 / L00;
    float L20 = d20 / L00;
    float L11 = sqrtf(d11 - L10 * L10);
    float L21 = (d21 - L20 * L10) / L11;
    float L22 = sqrtf(d22 - L20 * L20 - L21 * L21);

    // ---- write 12 floats as 3x nontemporal 16B stores (48B stride) ----
    floatx4* o = (floatx4*)(out + (size_t)p * 12);
    floatx4 o0 = {dr0, dr1, dr2, L00};
    floatx4 o1 = {0.0f, 0.0f, L10, L11};
    floatx4 o2 = {0.0f, L20, L21, L22};
    __builtin_nontemporal_store(o0, o + 0);
    __builtin_nontemporal_store(o1, o + 1);
    __builtin_nontemporal_store(o2, o + 2);
}

__global__ __launch_bounds__(256) void sde_kernel(
    const float* __restrict__ pot,    // (256,256,256)
    const float* __restrict__ vec,    // (256,256,256,3)
    const float* __restrict__ aff,    // 4x4 affine (row-major)
    const float* __restrict__ pos,    // (N,3)
    float* __restrict__ out,          // (N,12)
    int n)
{
    int half = (n + 1) >> 1;                 // 65536
    int p0 = blockIdx.x * 256 + threadIdx.x; // 0..half-1
    int p1 = p0 + half;

    if (p0 >= half) return;
    bool has1 = p1 < n;

    // ---- issue both pos loads up front (coalesced within wave) ----
    float2 a01 = *reinterpret_cast<const float2*>(pos + 3 * (size_t)p0);
    float  a2  = pos[3 * (size_t)p0 + 2];
    float2 b01 = make_float2(0.f, 0.f);
    float  b2  = 0.f;
    if (has1) {
        b01 = *reinterpret_cast<const float2*>(pos + 3 * (size_t)p1);
        b2  = pos[3 * (size_t)p1 + 2];
    }

    // ---- per-thread 4x4 adjugate inverse of the (uniform) affine ----
    float m[16];
#pragma unroll
    for (int i = 0; i < 16; ++i) m[i] = aff[i];

    float i0, i4, i8, i12, i1, i5, i9, i2, i6, i10, i3, i7, i11;
    i0  =  m[5]*m[10]*m[15] - m[5]*m[11]*m[14] - m[9]*m[6]*m[15] + m[9]*m[7]*m[14] + m[13]*m[6]*m[11] - m[13]*m[7]*m[10];
    i4  = -m[4]*m[10]*m[15] + m[4]*m[11]*m[14] + m[8]*m[6]*m[15] - m[8]*m[7]*m[14] - m[12]*m[6]*m[11] + m[12]*m[7]*m[10];
    i8  =  m[4]*m[9]*m[15]  - m[4]*m[11]*m[13] - m[8]*m[5]*m[15] + m[8]*m[7]*m[13] + m[12]*m[5]*m[11] - m[12]*m[7]*m[9];
    i12 = -m[4]*m[9]*m[14]  + m[4]*m[10]*m[13] + m[8]*m[5]*m[14] - m[8]*m[6]*m[13] - m[12]*m[5]*m[10] + m[12]*m[6]*m[9];
    i1  = -m[1]*m[10]*m[15] + m[1]*m[11]*m[14] + m[9]*m[2]*m[15] - m[9]*m[3]*m[14] - m[13]*m[2]*m[11] + m[13]*m[3]*m[10];
    i5  =  m[0]*m[10]*m[15] - m[0]*m[11]*m[14] - m[8]*m[2]*m[15] + m[8]*m[3]*m[14] + m[12]*m[2]*m[11] - m[12]*m[3]*m[10];
    i9  = -m[0]*m[9]*m[15]  + m[0]*m[11]*m[13] + m[8]*m[1]*m[15] - m[8]*m[3]*m[13] - m[12]*m[1]*m[11] + m[12]*m[3]*m[9];
    i2  =  m[1]*m[6]*m[15]  - m[1]*m[7]*m[14]  - m[5]*m[2]*m[15] + m[5]*m[3]*m[14] + m[13]*m[2]*m[7]  - m[13]*m[3]*m[6];
    i6  = -m[0]*m[6]*m[15]  + m[0]*m[7]*m[14]  + m[4]*m[2]*m[15] - m[4]*m[3]*m[14] - m[12]*m[2]*m[7]  + m[12]*m[3]*m[6];
    i10 =  m[0]*m[5]*m[15]  - m[0]*m[7]*m[13]  - m[4]*m[1]*m[15] + m[4]*m[3]*m[13] + m[12]*m[1]*m[7]  - m[12]*m[3]*m[5];
    i3  = -m[1]*m[6]*m[11]  + m[1]*m[7]*m[10]  + m[5]*m[2]*m[11] - m[5]*m[3]*m[10] - m[9]*m[2]*m[7]   + m[9]*m[3]*m[6];
    i7  =  m[0]*m[6]*m[11]  - m[0]*m[7]*m[10]  - m[4]*m[2]*m[11] + m[4]*m[3]*m[10] + m[8]*m[2]*m[7]   - m[8]*m[3]*m[6];
    i11 = -m[0]*m[5]*m[11]  + m[0]*m[7]*m[9]   + m[4]*m[1]*m[11] - m[4]*m[3]*m[9]  - m[8]*m[1]*m[7]   + m[8]*m[3]*m[5];

    float det = m[0]*i0 + m[1]*i4 + m[2]*i8 + m[3]*i12;
    float r = 1.0f / det;

    Ainv A;
    A.M00 = i0 * r;  A.M01 = i1 * r;  A.M02 = i2 * r;  A.T0 = i3 * r;
    A.M10 = i4 * r;  A.M11 = i5 * r;  A.M12 = i6 * r;  A.T1 = i7 * r;
    A.M20 = i8 * r;  A.M21 = i9 * r;  A.M22 = i10 * r; A.T2 = i11 * r;

    process_particle(pot, vec, A, a01.x, a01.y, a2, out, p0);
    if (has1)
        process_particle(pot, vec, A, b01.x, b01.y, b2, out, p1);
}

extern "C" void kernel_launch(void* const* d_in, const int* in_sizes, int n_in,
                              void* d_out, int out_size, void* d_ws, size_t ws_size,
                              hipStream_t stream) {
    const float* pot = (const float*)d_in[0];   // potential_field (256^3)
    const float* vec = (const float*)d_in[1];   // vector_field (256^3 x 3)
    const float* aff = (const float*)d_in[2];   // affine 4x4
    const float* pos = (const float*)d_in[3];   // positions (N,3)
    float* out = (float*)d_out;

    int n = in_sizes[3] / 3;
    int half = (n + 1) >> 1;
    int blocks = (half + 255) / 256;

    sde_kernel<<<blocks, 256, 0, stream>>>(pot, vec, aff, pos, out, n);
}